// Round 1
// 701.229 us; speedup vs baseline: 1.0323x; 1.0323x over previous
//
#include <hip/hip_runtime.h>
#include <math.h>

#define BATCH  512
#define SEQ    2048
#define INPUT  64
#define HID    128
#define LB     8
#define NG     24              // 3*LB; slab layout [s][b][j][3] = (r,z,n) per j
#define T      16              // timesteps per chunk
#define NCHUNK (SEQ / T)       // 128
#define SLABF  (LB * NG)       // 192 floats per 8-batch timestep slab
#define CH_F   (T * SLABF)     // 3072 floats per chunk gate buffer
#define ROWS   (T * LB)        // 128 A-rows per chunk (r = bh*16 + sw)
#define AF4C   (ROWS * 16)     // 2048 float4 per A chunk (32 KB)

#define LOG2E  1.44269504088896340736f

typedef float v2f __attribute__((ext_vector_type(2)));

__device__ __forceinline__ v2f mk2(float a, float b) { v2f r; r.x = a; r.y = b; return r; }

#if __has_builtin(__builtin_amdgcn_exp2f)
#define EXP2F(x) __builtin_amdgcn_exp2f(x)
#else
#define EXP2F(x) __expf(0.69314718055994530942f * (x))
#endif

// ---------------------------------------------------------------------------
// Phase 0: fold fc_in + GRU input projection into one 24x64 matrix + bias,
// PRESCALED for exp2: rows r,z (g<16) by -log2e; rows n (g>=16) by +2*log2e.
// sigmoid(x) = rcp(1 + 2^(-log2e*x));  tanh(t) = 1 - 2*rcp(1 + 2^(2*log2e*t))
// ---------------------------------------------------------------------------
__global__ void precompute_kernel(const float* __restrict__ W_in,
                                  const float* __restrict__ b_in,
                                  const float* __restrict__ W_ih,
                                  const float* __restrict__ b_ih,
                                  const float* __restrict__ b_hh,
                                  float* __restrict__ Wc,   // [24][64] prescaled
                                  float* __restrict__ bc)   // [24]     prescaled
{
    int t = blockIdx.x * blockDim.x + threadIdx.x;
    if (t < NG * INPUT) {
        int g = t / INPUT, i = t % INPUT;
        float acc = 0.f;
        for (int h = 0; h < HID; ++h)
            acc += W_ih[g * HID + h] * W_in[h * INPUT + i];
        float sc = (g < 2 * LB) ? -LOG2E : 2.0f * LOG2E;
        Wc[t] = acc * sc;
    } else if (t < NG * INPUT + NG) {
        int g = t - NG * INPUT;
        float acc = b_ih[g];
        if (g < 2 * LB) acc += b_hh[g];
        for (int h = 0; h < HID; ++h)
            acc += W_ih[g * HID + h] * b_in[h];
        float sc = (g < 2 * LB) ? -LOG2E : 2.0f * LOG2E;
        bc[g] = acc * sc;
    }
}

// ---------------------------------------------------------------------------
// Fused kernel: 64 blocks x 256 threads (4 waves -> 4 SIMDs/CU).
//   waves 0-2 (producers): A chunk -> LDS via global_load_lds (dbuf, source
//     XOR-swizzled with key (r>>3)&7, read applies the same key), then each
//     lane computes 2 gates x 8 rows with packed-fp32 dots (weights held in
//     128 VGPRs), writing the prescaled (r,z,n) slab.
//   wave 3 (consumer): validated DPP recurrence; exp2-prescaled gates feed
//     v_exp_f32 directly; packed v2f dot products.
// One __syncthreads per chunk, 129 barriers on every wave.
// ---------------------------------------------------------------------------
#define ROR2(v)  __int_as_float(__builtin_amdgcn_update_dpp(0, __float_as_int(v), 0x122, 0xF, 0xF, false))
#define ROR4(v)  __int_as_float(__builtin_amdgcn_update_dpp(0, __float_as_int(v), 0x124, 0xF, 0xF, false))
#define ROR8(v)  __int_as_float(__builtin_amdgcn_update_dpp(0, __float_as_int(v), 0x128, 0xF, 0xF, false))

#define GATHER8(sl, x) do {      \
    sl[0] = (x);                 \
    sl[1] = ROR2(sl[0]);         \
    sl[2] = ROR4(sl[0]);         \
    sl[3] = ROR4(sl[1]);         \
    sl[4] = ROR8(sl[0]);         \
    sl[5] = ROR8(sl[1]);         \
    sl[6] = ROR8(sl[2]);         \
    sl[7] = ROR8(sl[3]);         \
} while (0)

__global__ __launch_bounds__(256, 1) void fused_kernel(
    const float* __restrict__ A,     // [B][S][64]
    const float* __restrict__ Wc,    // [24][64] prescaled
    const float* __restrict__ bc,    // [24]     prescaled
    const float* __restrict__ W_hh,  // [24][8]  raw
    const float* __restrict__ b_hh,  // [24]     raw
    float* __restrict__ out)         // [B][8]
{
    __shared__ float4 abuf[2][AF4C];   // 64 KB: A chunk double buffer
    __shared__ float  sbuf[2][CH_F];   // 24 KB: gate slab double buffer

    const int tid = threadIdx.x;
    const int wv  = tid >> 6;
    const int l   = tid & 63;
    const int b0  = blockIdx.x * 8;

    if (wv < 3) {
        // ---------------- producers (3 waves, 192 lanes) ----------------
        const int pg = wv * 64 + l;        // 0..191
        const int gp = pg % 12;            // gate pair
        const int rg = pg / 12;            // row group, 0..15 (8 rows each)
        const int g0 = gp * 2, g1 = g0 + 1;
        const int j0 = g0 & 7, t0 = g0 >> 3;
        const int j1 = g1 & 7, t1 = g1 >> 3;

        // register-resident prescaled weights for this lane's 2 gates
        v2f w0l[16], w0h[16], w1l[16], w1h[16];
        const float4* W4 = (const float4*)Wc;
#pragma unroll
        for (int i = 0; i < 16; ++i) {
            float4 a = W4[g0 * 16 + i];
            float4 b = W4[g1 * 16 + i];
            w0l[i] = mk2(a.x, a.y); w0h[i] = mk2(a.z, a.w);
            w1l[i] = mk2(b.x, b.y); w1h[i] = mk2(b.z, b.w);
        }
        const float bc0 = bc[g0], bc1 = bc[g1];

        auto stage = [&](int cc) {
            float4* ab = &abuf[cc & 1][0];
            const size_t srow = (size_t)cc * T;
#pragma unroll
            for (int k = 0; k < 11; ++k) {
                int kk = k * 3 + wv;               // wave-uniform
                if (kk < 32) {
                    int q = kk * 64 + l;           // f4 index 0..2047
                    int r = q >> 4;                // row = bh*16 + sw
                    int i = q & 15;
                    int isrc = i ^ ((r >> 3) & 7); // pre-swizzled source
                    const float* gsrc = A
                        + ((size_t)(b0 + (r >> 4)) * SEQ + srow + (size_t)(r & 15)) * INPUT
                        + isrc * 4;
                    __builtin_amdgcn_global_load_lds(
                        (const __attribute__((address_space(1))) unsigned int*)gsrc,
                        (__attribute__((address_space(3))) unsigned int*)(ab + kk * 64),
                        16, 0, 0);
                }
            }
        };

        auto compute_slab = [&](int cc) {
            const float4* ab = &abuf[cc & 1][0];
            float* sl = &sbuf[cc & 1][0];
#pragma unroll
            for (int rit = 0; rit < 8; ++rit) {
                const int r  = rg * 8 + rit;
                const int xk = (r >> 3) & 7;       // same key as stage
                const float4* arow = ab + r * 16;
                v2f acc0 = mk2(bc0, 0.f);
                v2f acc1 = mk2(bc1, 0.f);
#pragma unroll
                for (int i = 0; i < 16; ++i) {
                    float4 a4 = arow[i ^ xk];      // = logical A f4 (r, i)
                    v2f alo = mk2(a4.x, a4.y);
                    v2f ahi = mk2(a4.z, a4.w);
                    acc0 = acc0 + alo * w0l[i] + ahi * w0h[i];
                    acc1 = acc1 + alo * w1l[i] + ahi * w1h[i];
                }
                const int sw = r & 15, bh = r >> 4;
                float* sp = sl + sw * SLABF + bh * (LB * 3);
                sp[j0 * 3 + t0] = acc0.x + acc0.y;
                sp[j1 * 3 + t1] = acc1.x + acc1.y;
            }
        };

        // prologue: chunk 0 staged+computed, chunk 1 staged
        stage(0);
        asm volatile("s_waitcnt vmcnt(0)" ::: "memory");
        __syncthreads();                           // B0: abuf[0] ready
        stage(1);
        compute_slab(0);
        asm volatile("s_waitcnt vmcnt(0)" ::: "memory");
        __syncthreads();                           // B1: sbuf[0]+abuf[1] ready

        for (int p = 0; p < NCHUNK; ++p) {
            if (p + 2 < NCHUNK) stage(p + 2);      // -> abuf[p&1] (free)
            if (p + 1 < NCHUNK) {
                compute_slab(p + 1);               // abuf[(p+1)&1] -> sbuf[(p+1)&1]
                asm volatile("s_waitcnt vmcnt(0)" ::: "memory");
                __syncthreads();
            }
        }
    } else {
        // ---------------- consumer (wave 3) ----------------
        const int row = l >> 4;
        const int j   = (l >> 1) & 7;
        const int g   = l & 1;
        const int bh  = row * 2 + g;
        const int b   = b0 + bh;
        const int cofs = (bh * LB + j) * 3;

        // slot -> hidden-index map, resolved at runtime through the DPP net
        float jdxv[8];
        GATHER8(jdxv, (float)j);
        float wrs[8], wzs[8], wns[8];
#pragma unroll
        for (int m = 0; m < 8; ++m) {
            int idx = (int)(jdxv[m] + 0.5f);
            wrs[m] = W_hh[(0 * LB + j) * LB + idx] * (-LOG2E);
            wzs[m] = W_hh[(1 * LB + j) * LB + idx] * (-LOG2E);
            wns[m] = W_hh[(2 * LB + j) * LB + idx] * (2.0f * LOG2E);
        }
        v2f wr2[4], wz2[4], wn2[4];
#pragma unroll
        for (int m = 0; m < 4; ++m) {
            wr2[m] = mk2(wrs[2 * m], wrs[2 * m + 1]);
            wz2[m] = mk2(wzs[2 * m], wzs[2 * m + 1]);
            wn2[m] = mk2(wns[2 * m], wns[2 * m + 1]);
        }
        const float bhn = b_hh[2 * LB + j] * (2.0f * LOG2E);

        float h = 0.f;
        __syncthreads();                           // B0
        __syncthreads();                           // B1: sbuf[0] ready

        for (int p = 0; p < NCHUNK; ++p) {
            const float* Lb = &sbuf[p & 1][cofs];

            // 2-deep rotating LDS->reg prefetch
            float cr = Lb[0],         cz = Lb[1],         cn = Lb[2];
            float nr = Lb[SLABF + 0], nz = Lb[SLABF + 1], nn = Lb[SLABF + 2];
#pragma unroll
            for (int d = 0; d < T; ++d) {
                float fr = 0.f, fz = 0.f, fn = 0.f;
                if (d + 2 < T) {
                    const float* q = Lb + (d + 2) * SLABF;
                    fr = q[0]; fz = q[1]; fn = q[2];
                }

                float hs[8];
                GATHER8(hs, h);
                v2f h0 = mk2(hs[0], hs[1]);
                v2f h1 = mk2(hs[2], hs[3]);
                v2f h2 = mk2(hs[4], hs[5]);
                v2f h3 = mk2(hs[6], hs[7]);

                v2f srv = h0 * wr2[0] + h1 * wr2[1] + (h2 * wr2[2] + h3 * wr2[3]);
                v2f szv = h0 * wz2[0] + h1 * wz2[1] + (h2 * wz2[2] + h3 * wz2[3]);
                v2f snv = h0 * wn2[0] + h1 * wn2[1] + (h2 * wn2[2] + h3 * wn2[3]);

                float dr = cr + (srv.x + srv.y);   // already -log2e scaled
                float dz = cz + (szv.x + szv.y);
                float dn = bhn + (snv.x + snv.y);  // already 2*log2e scaled

                float er = EXP2F(dr);
                float ez = EXP2F(dz);
                float rr = __builtin_amdgcn_rcpf(1.f + er);  // sigmoid(dr_orig)
                float zz = __builtin_amdgcn_rcpf(1.f + ez);

                float tt = fmaf(rr, dn, cn);       // = 2*log2e * t_orig
                float en = EXP2F(tt);              // = exp(2*t_orig)
                float nv = fmaf(-2.f, __builtin_amdgcn_rcpf(1.f + en), 1.f); // tanh(t)

                h = fmaf(zz, h - nv, nv);

                cr = nr; cz = nz; cn = nn;
                nr = fr; nz = fz; nn = fn;
            }
            if (p + 1 < NCHUNK) __syncthreads();
        }

        out[b * LB + j] = h;
    }
}

// ---------------------------------------------------------------------------
extern "C" void kernel_launch(void* const* d_in, const int* in_sizes, int n_in,
                              void* d_out, int out_size, void* d_ws, size_t ws_size,
                              hipStream_t stream) {
    const float* A    = (const float*)d_in[0];  // (512, 2048, 64)
    const float* W_in = (const float*)d_in[1];  // (128, 64)
    const float* b_in = (const float*)d_in[2];  // (128,)
    const float* W_ih = (const float*)d_in[3];  // (24, 128)
    const float* W_hh = (const float*)d_in[4];  // (24, 8)
    const float* b_ih = (const float*)d_in[5];  // (24,)
    const float* b_hh = (const float*)d_in[6];  // (24,)
    float* out = (float*)d_out;                 // (512, 8)

    // workspace: Wc [24][64] | bc [24]   (gates tensor eliminated)
    float* Wc = (float*)d_ws;
    float* bc = Wc + NG * INPUT;

    precompute_kernel<<<7, 256, 0, stream>>>(W_in, b_in, W_ih, b_ih, b_hh, Wc, bc);
    fused_kernel<<<BATCH / 8, 256, 0, stream>>>(A, Wc, bc, W_hh, b_hh, out);
}